// Round 12
// baseline (126.391 us; speedup 1.0000x reference)
//
#include <hip/hip_runtime.h>

#define BB 4
#define NN 4096        // 64*64 spatial
#define CQK 64
#define DQ 16
#define CV 128

typedef __attribute__((ext_vector_type(8))) short bf16x8;
typedef __attribute__((ext_vector_type(4))) float f32x4;
typedef __attribute__((ext_vector_type(16))) float f32x16;
typedef __attribute__((ext_vector_type(8))) unsigned short u16x8;

__device__ __forceinline__ unsigned short f2bf(float f) {
    unsigned int u = __builtin_bit_cast(unsigned int, f);
    u += 0x7FFFu + ((u >> 16) & 1u);   // RNE
    return (unsigned short)(u >> 16);
}
// truncation-pack two fp32 -> packed bf16x2 (v_perm_b32-foldable)
__device__ __forceinline__ unsigned int pk_trunc(float lo, float hi) {
    unsigned int a = __builtin_bit_cast(unsigned int, lo);
    unsigned int b = __builtin_bit_cast(unsigned int, hi);
    return (a >> 16) | (b & 0xFFFF0000u);
}

// ================= fused projections (R11-verified, unchanged) =================
// blocks 0..511:   V projection (2 blocks per 64-pos tile, 64 out-chans each)
// blocks 512..575: Q/K projection (256 positions per block)
__global__ __launch_bounds__(256, 4) void proj(
    const float* __restrict__ x,   // [B][64][N]
    const float* __restrict__ Wq, const float* __restrict__ bq,
    const float* __restrict__ Wk, const float* __restrict__ bk,
    const float* __restrict__ xh,  // [B][128][N]
    const float* __restrict__ Wv, const float* __restrict__ bv,
    unsigned short* __restrict__ qT, unsigned short* __restrict__ kT,
    unsigned short* __restrict__ vB)
{
    __shared__ __align__(16) float smem[8448];
    int tid = threadIdx.x;
    if (blockIdx.x < 512) {
        // ---------- V projection ----------
        float* wvT = smem;            // [64 ci][66]
        float* xs  = smem + 4224;     // [64 ci][64 pos]
        float* bvs = smem + 8320;     // [64]
        int pt = blockIdx.x >> 1, h = blockIdx.x & 1;
        int i0 = pt * 64;
        int b = i0 >> 12, ib = i0 & 4095;
        int co0 = h * 64;
        if (tid < 64) bvs[tid] = bv[co0 + tid];
        int cog = tid & 31, ig = tid >> 5;   // 2 out-chans, 8 positions
        float acc[8][2];
#pragma unroll
        for (int q = 0; q < 8; q++) { acc[q][0] = 0.f; acc[q][1] = 0.f; }

        for (int ch = 0; ch < 2; ch++) {
            for (int t = tid; t < 4096; t += 256) {
                int c = t & 63, col = t >> 6;
                wvT[c * 66 + col] = Wv[(size_t)(co0 + col) * CV + ch * 64 + c];
            }
            for (int t = tid; t < 4096; t += 256) {
                int il = t & 63, c = t >> 6;
                xs[c * 64 + il] = xh[((size_t)b * CV + ch * 64 + c) * NN + ib + il];
            }
            __syncthreads();
            for (int c = 0; c < 64; c++) {
                float2 w2 = *(const float2*)&wvT[c * 66 + cog * 2];
                float4 xa = *(const float4*)&xs[c * 64 + ig * 8];
                float4 xb = *(const float4*)&xs[c * 64 + ig * 8 + 4];
                float xv[8] = { xa.x, xa.y, xa.z, xa.w, xb.x, xb.y, xb.z, xb.w };
#pragma unroll
                for (int q = 0; q < 8; q++) {
                    acc[q][0] += xv[q] * w2.x;
                    acc[q][1] += xv[q] * w2.y;
                }
            }
            __syncthreads();
        }
        // swizzled store: vB per 64-key tile = [chunk(2)][n(8)][lane(64)][jj(8)]
        int kt = ib >> 6;
        int chunk = ig >> 2, quad = ig & 3;
#pragma unroll
        for (int cc = 0; cc < 2; cc++) {
            int co = co0 + cog * 2 + cc;
            int n = co >> 4, cl = co & 15;
            float bb = bvs[cog * 2 + cc];
            u16x8 o;
#pragma unroll
            for (int jj = 0; jj < 8; jj++) o[jj] = f2bf(acc[jj][cc] + bb);
            size_t base = ((size_t)(b * 64 + kt)) * 8192
                        + (size_t)(((chunk * 8 + n) * 64 + quad * 16 + cl)) * 8;
            *(u16x8*)(vB + base) = o;
        }
    } else {
        // ---------- Q/K projection ----------
        float* wqT = smem;          // [64 c][16 d]
        float* wkT = smem + 1024;
        float* bqs = smem + 2048;
        float* bks = smem + 2064;
        for (int t = tid; t < 1024; t += 256) {
            int c = t & 63, d = t >> 6;          // coalesced global read
            wqT[c * 16 + d] = Wq[d * CQK + c];
            wkT[c * 16 + d] = Wk[d * CQK + c];
        }
        if (tid < DQ) { bqs[tid] = bq[tid]; bks[tid] = bk[tid]; }
        __syncthreads();

        int gidx = (blockIdx.x - 512) * 256 + tid;   // over B*N
        int b = gidx >> 12, i = gidx & 4095;
        float qa[DQ], ka[DQ];
#pragma unroll
        for (int d = 0; d < DQ; d++) { qa[d] = bqs[d]; ka[d] = bks[d]; }
        const float* xp = x + (size_t)b * CQK * NN + i;
        for (int c = 0; c < CQK; c++) {
            float xv = xp[(size_t)c * NN];
            const float4* wq4 = (const float4*)&wqT[c * DQ];
            const float4* wk4 = (const float4*)&wkT[c * DQ];
#pragma unroll
            for (int dd = 0; dd < 4; dd++) {
                float4 a = wq4[dd], e = wk4[dd];
                qa[dd*4+0] += a.x * xv; qa[dd*4+1] += a.y * xv;
                qa[dd*4+2] += a.z * xv; qa[dd*4+3] += a.w * xv;
                ka[dd*4+0] += e.x * xv; ka[dd*4+1] += e.y * xv;
                ka[dd*4+2] += e.z * xv; ka[dd*4+3] += e.w * xv;
            }
        }
        u16x8 q0, q1, k0, k1;
#pragma unroll
        for (int dd = 0; dd < 8; dd++) {
            q0[dd] = f2bf(qa[dd]);     q1[dd] = f2bf(qa[8 + dd]);
            k0[dd] = f2bf(ka[dd]);     k1[dd] = f2bf(ka[8 + dd]);
        }
        u16x8* qo = (u16x8*)(qT + (size_t)gidx * DQ);
        u16x8* ko = (u16x8*)(kT + (size_t)gidx * DQ);
        qo[0] = q0; qo[1] = q1;
        ko[0] = k0; ko[1] = k1;
    }
}

// ================= MFMA flash attention, 64 queries/block =================
// block = one 64-query group; wave w owns key tiles w*16..w*16+15 (split-K).
// Halves V+K L2 traffic vs 32q (256 blocks x 1MB V). 1 block/CU, high-VGPR:
// __launch_bounds__(256,1) = loosest bound, budget 512, ~290 live (acc 128 +
// vb 64 + s 64 + kb/qa 16). Do NOT raise min-waves (R7: spill -> 510MB FETCH).
// QK^T: 4x v_mfma_f32_32x32x16_bf16 (S^T = K·Q^T, K=16 exact).
// PV: 4 q16-groups x 2ch x 8 chan-groups of 16x16x32 sharing vb loads.
// accs merge buffer ALIASES dead pT region (barrier before overlay).
__global__ __launch_bounds__(256, 1) void flash_mfma(
    const unsigned short* __restrict__ qTb,  // [B*N][16] bf16
    const unsigned short* __restrict__ kTb,  // [B*N][16] bf16
    const unsigned short* __restrict__ vB,   // swizzled bf16
    const float* __restrict__ xh,            // [B][128][N]
    const float* __restrict__ gamma,
    float* __restrict__ out)                 // [B][128][N]
{
    // pT: [w 4][q 64][key pad72] shorts = 36864 B; accs aliases it after K-loop:
    // [c 128][q pad68] floats = 34816 B.
    __shared__ __align__(16) unsigned char smem[36864];
    __shared__ float l_s[16 * 32];           // [(w*2+half)*2+g][q32]

    int tid = threadIdx.x;
    int w = tid >> 6, lane = tid & 63;
    int q32 = lane & 31, half = lane >> 5;
    int quad = lane >> 4, cl = lane & 15;
    int b = blockIdx.x >> 6;                 // 64 q-groups of 64 per batch
    int i0 = (blockIdx.x & 63) * 64;
    const f32x4 zf = {0.f, 0.f, 0.f, 0.f};
    f32x16 zf16;
#pragma unroll
    for (int r = 0; r < 16; r++) zf16[r] = 0.f;

    // Q B-frags (32x32x16): B[k=half*8+j][n=q32], two q32-groups
    bf16x8 qa[2];
#pragma unroll
    for (int g = 0; g < 2; g++)
        qa[g] = *(const bf16x8*)(qTb + ((size_t)(b * NN + i0 + g * 32 + q32)) * DQ + half * 8);

    f32x4 acc[4][8];
#pragma unroll
    for (int gg = 0; gg < 4; gg++)
#pragma unroll
        for (int n = 0; n < 8; n++) acc[gg][n] = zf;
    float l[2] = {0.f, 0.f};

    const unsigned short* vtile = vB + ((size_t)(b * 64 + w * 16)) * 8192;
    const unsigned short* kbase = kTb + ((size_t)(b * NN + w * 16 * 64)) * DQ;
    unsigned short* pTw = (unsigned short*)smem + w * 64 * 72;

    // prefetch tile 0: K A-frags (A[m=key=q32][k=half*8+j]) + V B-frags
    bf16x8 kb[2], vb[16];
#pragma unroll
    for (int mg = 0; mg < 2; mg++)
        kb[mg] = *(const bf16x8*)(kbase + (size_t)(mg * 32 + q32) * DQ + half * 8);
#pragma unroll
    for (int i = 0; i < 16; i++)
        vb[i] = *(const bf16x8*)(vtile + (size_t)i * 512 + (size_t)lane * 8);

    for (int t = 0; t < 16; t++) {
        // --- S^T = K·Q^T : 2 key-halves x 2 q32-groups ---
        f32x16 s[4];
#pragma unroll
        for (int g = 0; g < 2; g++)
#pragma unroll
            for (int mg = 0; mg < 2; mg++)
                s[g * 2 + mg] = __builtin_amdgcn_mfma_f32_32x32x16_bf16(kb[mg], qa[g], zf16, 0, 0, 0);
        const unsigned short* ktn = kbase + (size_t)(((t + 1) & 15) * 64) * DQ;
#pragma unroll
        for (int mg = 0; mg < 2; mg++)
            kb[mg] = *(const bf16x8*)(ktn + (size_t)(mg * 32 + q32) * DQ + half * 8);

        // --- p = exp(s): q = g*32+q32, key = mg*32 + rr*8 + half*4 + 0..3 ---
#pragma unroll
        for (int g = 0; g < 2; g++) {
#pragma unroll
            for (int mg = 0; mg < 2; mg++) {
#pragma unroll
                for (int rr = 0; rr < 4; rr++) {
                    float p0 = __expf(s[g * 2 + mg][rr * 4 + 0]);
                    float p1 = __expf(s[g * 2 + mg][rr * 4 + 1]);
                    float p2 = __expf(s[g * 2 + mg][rr * 4 + 2]);
                    float p3 = __expf(s[g * 2 + mg][rr * 4 + 3]);
                    l[g] += (p0 + p1) + (p2 + p3);
                    *(uint2*)(pTw + (size_t)(g * 32 + q32) * 72 + mg * 32 + rr * 8 + half * 4) =
                        make_uint2(pk_trunc(p0, p1), pk_trunc(p2, p3));
                }
            }
        }

        // --- O += P·V : 4 q16-groups share the 16 vb fragments ---
        const unsigned short* vtn = vtile + ((t < 15) ? 8192 : 0);
#pragma unroll
        for (int ch = 0; ch < 2; ch++) {
            bf16x8 pa[4];
#pragma unroll
            for (int gg = 0; gg < 4; gg++)
                pa[gg] = *(const bf16x8*)(pTw + (size_t)(gg * 16 + cl) * 72 + ch * 32 + quad * 8);
#pragma unroll
            for (int n = 0; n < 8; n++) {
#pragma unroll
                for (int gg = 0; gg < 4; gg++)
                    acc[gg][n] = __builtin_amdgcn_mfma_f32_16x16x32_bf16(pa[gg], vb[ch * 8 + n], acc[gg][n], 0, 0, 0);
            }
#pragma unroll
            for (int n = 0; n < 8; n++)
                vb[ch * 8 + n] = *(const bf16x8*)(vtn + (size_t)(ch * 8 + n) * 512 + (size_t)lane * 8);
        }
        vtile = vtn;
    }

    // --- merge: l to LDS, then accs (ALIASES pT -> barrier first) ---
#pragma unroll
    for (int g = 0; g < 2; g++)
        l_s[((w * 2 + half) * 2 + g) * 32 + q32] = l[g];
    __syncthreads();                         // all waves done reading pT
    float* accs = (float*)smem;              // [c 128][q pad68]
    for (int ww = 0; ww < 4; ww++) {
        if (w == ww) {
#pragma unroll
            for (int gg = 0; gg < 4; gg++)
#pragma unroll
                for (int n = 0; n < 8; n++) {
                    float* p = accs + (size_t)(n * 16 + cl) * 68 + gg * 16 + quad * 4;
                    if (ww == 0) *(f32x4*)p = acc[gg][n];
                    else {
                        f32x4 o = *(const f32x4*)p;
                        *(f32x4*)p = o + acc[gg][n];
                    }
                }
        }
        __syncthreads();
    }

    // --- epilogue: q = tid&63, 32 channels each ---
    float gam = gamma[0];
    int q = tid & 63, cgrp = tid >> 6;
    int qg = q >> 5, qq = q & 31;
    float L = 0.f;
#pragma unroll
    for (int u = 0; u < 8; u++) L += l_s[(u * 2 + qg) * 32 + qq];
    float linv = 1.f / L;
#pragma unroll
    for (int cc = 0; cc < 32; cc++) {
        int c = cgrp * 32 + cc;
        size_t gi = ((size_t)(b * CV + c)) * NN + i0 + q;
        out[gi] = gam * accs[(size_t)c * 68 + q] * linv + xh[gi];
    }
}

extern "C" void kernel_launch(void* const* d_in, const int* in_sizes, int n_in,
                              void* d_out, int out_size, void* d_ws, size_t ws_size,
                              hipStream_t stream)
{
    (void)in_sizes; (void)n_in; (void)out_size; (void)ws_size;
    const float* x  = (const float*)d_in[0];
    const float* xh = (const float*)d_in[1];
    const float* Wq = (const float*)d_in[2];
    const float* bq = (const float*)d_in[3];
    const float* Wk = (const float*)d_in[4];
    const float* bk = (const float*)d_in[5];
    const float* Wv = (const float*)d_in[6];
    const float* bv = (const float*)d_in[7];
    const float* gm = (const float*)d_in[8];
    float* out = (float*)d_out;

    char* ws = (char*)d_ws;
    unsigned short* qTb = (unsigned short*)ws;                      // 512 KB
    unsigned short* kTb = (unsigned short*)(ws + (512 << 10));      // 512 KB
    unsigned short* vB  = (unsigned short*)(ws + (1 << 20));        // 4 MB

    proj<<<576, 256, 0, stream>>>(x, Wq, bq, Wk, bk, xh, Wv, bv, qTb, kTb, vB);
    flash_mfma<<<BB * 64, 256, 0, stream>>>(qTb, kTb, vB, xh, gm, out);
}

// Round 13
// 122.562 us; speedup vs baseline: 1.0312x; 1.0312x over previous
//
#include <hip/hip_runtime.h>

#define BB 4
#define NN 4096        // 64*64 spatial
#define CQK 64
#define DQ 16
#define CV 128

typedef __attribute__((ext_vector_type(8))) short bf16x8;
typedef __attribute__((ext_vector_type(4))) float f32x4;
typedef __attribute__((ext_vector_type(16))) float f32x16;
typedef __attribute__((ext_vector_type(8))) unsigned short u16x8;

__device__ __forceinline__ unsigned short f2bf(float f) {
    unsigned int u = __builtin_bit_cast(unsigned int, f);
    u += 0x7FFFu + ((u >> 16) & 1u);   // RNE
    return (unsigned short)(u >> 16);
}
// truncation-pack two fp32 -> packed bf16x2 (v_perm_b32-foldable)
__device__ __forceinline__ unsigned int pk_trunc(float lo, float hi) {
    unsigned int a = __builtin_bit_cast(unsigned int, lo);
    unsigned int b = __builtin_bit_cast(unsigned int, hi);
    return (a >> 16) | (b & 0xFFFF0000u);
}

// ================= fused projections =================
// blocks 0..511:   V projection (2 blocks per 64-pos tile, 64 out-chans each)
// blocks 512..575: Q/K projection (256 positions per block)
__global__ __launch_bounds__(256, 4) void proj(
    const float* __restrict__ x,   // [B][64][N]
    const float* __restrict__ Wq, const float* __restrict__ bq,
    const float* __restrict__ Wk, const float* __restrict__ bk,
    const float* __restrict__ xh,  // [B][128][N]
    const float* __restrict__ Wv, const float* __restrict__ bv,
    unsigned short* __restrict__ qT, unsigned short* __restrict__ kT,
    unsigned short* __restrict__ vB)
{
    __shared__ __align__(16) float smem[8448];
    int tid = threadIdx.x;
    if (blockIdx.x < 512) {
        // ---------- V projection ----------
        float* wvT = smem;            // [64 ci][66]
        float* xs  = smem + 4224;     // [64 ci][64 pos]
        float* bvs = smem + 8320;     // [64]
        int pt = blockIdx.x >> 1, h = blockIdx.x & 1;
        int i0 = pt * 64;
        int b = i0 >> 12, ib = i0 & 4095;
        int co0 = h * 64;
        if (tid < 64) bvs[tid] = bv[co0 + tid];
        int cog = tid & 31, ig = tid >> 5;   // 2 out-chans, 8 positions
        float acc[8][2];
#pragma unroll
        for (int q = 0; q < 8; q++) { acc[q][0] = 0.f; acc[q][1] = 0.f; }

        for (int ch = 0; ch < 2; ch++) {
            for (int t = tid; t < 4096; t += 256) {
                int c = t & 63, col = t >> 6;
                wvT[c * 66 + col] = Wv[(size_t)(co0 + col) * CV + ch * 64 + c];
            }
            for (int t = tid; t < 4096; t += 256) {
                int il = t & 63, c = t >> 6;
                xs[c * 64 + il] = xh[((size_t)b * CV + ch * 64 + c) * NN + ib + il];
            }
            __syncthreads();
            for (int c = 0; c < 64; c++) {
                float2 w2 = *(const float2*)&wvT[c * 66 + cog * 2];
                float4 xa = *(const float4*)&xs[c * 64 + ig * 8];
                float4 xb = *(const float4*)&xs[c * 64 + ig * 8 + 4];
                float xv[8] = { xa.x, xa.y, xa.z, xa.w, xb.x, xb.y, xb.z, xb.w };
#pragma unroll
                for (int q = 0; q < 8; q++) {
                    acc[q][0] += xv[q] * w2.x;
                    acc[q][1] += xv[q] * w2.y;
                }
            }
            __syncthreads();
        }
        // swizzled store: vB per 64-key tile = [chunk(2)][n(8)][lane(64)][jj(8)]
        int kt = ib >> 6;
        int chunk = ig >> 2, quad = ig & 3;
#pragma unroll
        for (int cc = 0; cc < 2; cc++) {
            int co = co0 + cog * 2 + cc;
            int n = co >> 4, cl = co & 15;
            float bb = bvs[cog * 2 + cc];
            u16x8 o;
#pragma unroll
            for (int jj = 0; jj < 8; jj++) o[jj] = f2bf(acc[jj][cc] + bb);
            size_t base = ((size_t)(b * 64 + kt)) * 8192
                        + (size_t)(((chunk * 8 + n) * 64 + quad * 16 + cl)) * 8;
            *(u16x8*)(vB + base) = o;
        }
    } else {
        // ---------- Q/K projection ----------
        float* wqT = smem;          // [64 c][16 d]
        float* wkT = smem + 1024;
        float* bqs = smem + 2048;
        float* bks = smem + 2064;
        for (int t = tid; t < 1024; t += 256) {
            int c = t & 63, d = t >> 6;          // coalesced global read
            wqT[c * 16 + d] = Wq[d * CQK + c];
            wkT[c * 16 + d] = Wk[d * CQK + c];
        }
        if (tid < DQ) { bqs[tid] = bq[tid]; bks[tid] = bk[tid]; }
        __syncthreads();

        int gidx = (blockIdx.x - 512) * 256 + tid;   // over B*N
        int b = gidx >> 12, i = gidx & 4095;
        float qa[DQ], ka[DQ];
#pragma unroll
        for (int d = 0; d < DQ; d++) { qa[d] = bqs[d]; ka[d] = bks[d]; }
        const float* xp = x + (size_t)b * CQK * NN + i;
        for (int c = 0; c < CQK; c++) {
            float xv = xp[(size_t)c * NN];
            const float4* wq4 = (const float4*)&wqT[c * DQ];
            const float4* wk4 = (const float4*)&wkT[c * DQ];
#pragma unroll
            for (int dd = 0; dd < 4; dd++) {
                float4 a = wq4[dd], e = wk4[dd];
                qa[dd*4+0] += a.x * xv; qa[dd*4+1] += a.y * xv;
                qa[dd*4+2] += a.z * xv; qa[dd*4+3] += a.w * xv;
                ka[dd*4+0] += e.x * xv; ka[dd*4+1] += e.y * xv;
                ka[dd*4+2] += e.z * xv; ka[dd*4+3] += e.w * xv;
            }
        }
        u16x8 q0, q1, k0, k1;
#pragma unroll
        for (int dd = 0; dd < 8; dd++) {
            q0[dd] = f2bf(qa[dd]);     q1[dd] = f2bf(qa[8 + dd]);
            k0[dd] = f2bf(ka[dd]);     k1[dd] = f2bf(ka[8 + dd]);
        }
        u16x8* qo = (u16x8*)(qT + (size_t)gidx * DQ);
        u16x8* ko = (u16x8*)(kT + (size_t)gidx * DQ);
        qo[0] = q0; qo[1] = q1;
        ko[0] = k0; ko[1] = k1;
    }
}

// ================= MFMA flash attention, 32 queries/block =================
// block = one 32-query group; wave w owns key tiles w*16..w*16+15 (split-K).
// QK^T via v_mfma_f32_32x32x16_bf16 (K=16 exact, no padding): S^T = K·Q^T,
// C: col=lane&31=q, row=key=(reg&3)+8*(reg>>2)+4*(lane>>5).
// PV via 2x 16x16x32 q-groups SHARING the vb loads (2x MFMA per V byte).
// p = exp(s) raw (scores bounded), truncation-packed to pT[q][key].
// (256,2): peak live ~210 VGPR; do NOT raise min-waves (R7 spill lesson:
// (256,6) spilled prefetch arrays -> 510MB FETCH, 3.8x regression).
// Tile-size sweep settled: 16q = latency-bound (R8, 51us), 64q = TLP-bound
// at 1 block/CU (R12, neutral-worse); 32q is the optimum (R11, champion).
// fp8 P·V attempt (R10) produced unexplained NaN -> bf16.
__global__ __launch_bounds__(256, 2) void flash_mfma(
    const unsigned short* __restrict__ qTb,  // [B*N][16] bf16
    const unsigned short* __restrict__ kTb,  // [B*N][16] bf16
    const unsigned short* __restrict__ vB,   // swizzled bf16
    const float* __restrict__ xh,            // [B][128][N]
    const float* __restrict__ gamma,
    float* __restrict__ out)                 // [B][128][N]
{
    __shared__ __align__(16) unsigned short pT[4 * 32 * 76];  // [w][q 32][key pad76]
    __shared__ __align__(16) float accs[128 * 36];            // [c 128][q pad36]
    __shared__ float l_s[4 * 2 * 32];                         // [w][half][q]

    int tid = threadIdx.x;
    int w = tid >> 6, lane = tid & 63;
    int q32 = lane & 31, half = lane >> 5;
    int quad = lane >> 4, cl = lane & 15;
    int b = blockIdx.x >> 7;                  // 128 q-groups of 32 per batch
    int i0 = (blockIdx.x & 127) * 32;
    const f32x4 zf = {0.f, 0.f, 0.f, 0.f};
    f32x16 zf16;
#pragma unroll
    for (int r = 0; r < 16; r++) zf16[r] = 0.f;

    // Q B-frag (32x32x16): B[k=half*8+j][n=q32] — full K=16, no padding
    bf16x8 qa = *(const bf16x8*)(qTb + ((size_t)(b * NN + i0 + q32)) * DQ + half * 8);

    f32x4 acc[2][8];
#pragma unroll
    for (int g = 0; g < 2; g++)
#pragma unroll
        for (int n = 0; n < 8; n++) acc[g][n] = zf;
    float l = 0.f;

    const unsigned short* vtile = vB + ((size_t)(b * 64 + w * 16)) * 8192;
    const unsigned short* kbase = kTb + ((size_t)(b * NN + w * 16 * 64)) * DQ;
    unsigned short* pTw = pT + w * 32 * 76;

    // prefetch tile 0: K A-frags (32x32x16: A[m=key=q32][k=half*8+j]) + V B-frags
    bf16x8 kb[2], vb[16];
#pragma unroll
    for (int mg = 0; mg < 2; mg++)
        kb[mg] = *(const bf16x8*)(kbase + (size_t)(mg * 32 + q32) * DQ + half * 8);
#pragma unroll
    for (int i = 0; i < 16; i++)
        vb[i] = *(const bf16x8*)(vtile + (size_t)i * 512 + (size_t)lane * 8);

    for (int t = 0; t < 16; t++) {
        // --- S^T = K·Q^T : two 32x32x16 (keys 0-31, 32-63) x 32 queries ---
        f32x16 s[2];
        s[0] = __builtin_amdgcn_mfma_f32_32x32x16_bf16(kb[0], qa, zf16, 0, 0, 0);
        s[1] = __builtin_amdgcn_mfma_f32_32x32x16_bf16(kb[1], qa, zf16, 0, 0, 0);
        const unsigned short* ktn = kbase + (size_t)(((t + 1) & 15) * 64) * DQ;
#pragma unroll
        for (int mg = 0; mg < 2; mg++)
            kb[mg] = *(const bf16x8*)(ktn + (size_t)(mg * 32 + q32) * DQ + half * 8);

        // --- p = exp(s): reg 4rr..4rr+3 -> keys mg*32 + rr*8 + half*4 + 0..3 ---
#pragma unroll
        for (int mg = 0; mg < 2; mg++) {
#pragma unroll
            for (int rr = 0; rr < 4; rr++) {
                float p0 = __expf(s[mg][rr * 4 + 0]);
                float p1 = __expf(s[mg][rr * 4 + 1]);
                float p2 = __expf(s[mg][rr * 4 + 2]);
                float p3 = __expf(s[mg][rr * 4 + 3]);
                l += (p0 + p1) + (p2 + p3);
                int k0 = mg * 32 + rr * 8 + half * 4;
                *(uint2*)(pTw + q32 * 76 + k0) =
                    make_uint2(pk_trunc(p0, p1), pk_trunc(p2, p3));
            }
        }

        // --- O += P·V : 2 q-groups share the 16 vb fragments ---
        const unsigned short* vtn = vtile + ((t < 15) ? 8192 : 0);
#pragma unroll
        for (int ch = 0; ch < 2; ch++) {
            bf16x8 pa0 = *(const bf16x8*)(pTw + (size_t)cl * 76 + ch * 32 + quad * 8);
            bf16x8 pa1 = *(const bf16x8*)(pTw + (size_t)(16 + cl) * 76 + ch * 32 + quad * 8);
#pragma unroll
            for (int n = 0; n < 8; n++) {
                acc[0][n] = __builtin_amdgcn_mfma_f32_16x16x32_bf16(pa0, vb[ch * 8 + n], acc[0][n], 0, 0, 0);
                acc[1][n] = __builtin_amdgcn_mfma_f32_16x16x32_bf16(pa1, vb[ch * 8 + n], acc[1][n], 0, 0, 0);
            }
#pragma unroll
            for (int n = 0; n < 8; n++)
                vb[ch * 8 + n] = *(const bf16x8*)(vtn + (size_t)(ch * 8 + n) * 512 + (size_t)lane * 8);
        }
        vtile = vtn;
    }

    // --- cross-wave merge, single [c][q] buffer, 4 serialized rounds ---
    l_s[(w * 2 + half) * 32 + q32] = l;
    for (int ww = 0; ww < 4; ww++) {
        if (w == ww) {
#pragma unroll
            for (int g = 0; g < 2; g++)
#pragma unroll
                for (int n = 0; n < 8; n++) {
                    float* p = accs + (n * 16 + cl) * 36 + g * 16 + quad * 4;
                    if (ww == 0) *(f32x4*)p = acc[g][n];
                    else {
                        f32x4 o = *(const f32x4*)p;
                        *(f32x4*)p = o + acc[g][n];
                    }
                }
        }
        __syncthreads();
    }

    // --- epilogue: 256 threads, q = tid&31, 16 channels each ---
    float gam = gamma[0];
    int q = tid & 31, cg = tid >> 5;
    float L = 0.f;
#pragma unroll
    for (int u = 0; u < 8; u++) L += l_s[u * 32 + q];
    float linv = 1.f / L;
#pragma unroll
    for (int cc = 0; cc < 16; cc++) {
        int c = cg * 16 + cc;
        size_t gi = ((size_t)(b * CV + c)) * NN + i0 + q;
        out[gi] = gam * accs[c * 36 + q] * linv + xh[gi];
    }
}

extern "C" void kernel_launch(void* const* d_in, const int* in_sizes, int n_in,
                              void* d_out, int out_size, void* d_ws, size_t ws_size,
                              hipStream_t stream)
{
    (void)in_sizes; (void)n_in; (void)out_size; (void)ws_size;
    const float* x  = (const float*)d_in[0];
    const float* xh = (const float*)d_in[1];
    const float* Wq = (const float*)d_in[2];
    const float* bq = (const float*)d_in[3];
    const float* Wk = (const float*)d_in[4];
    const float* bk = (const float*)d_in[5];
    const float* Wv = (const float*)d_in[6];
    const float* bv = (const float*)d_in[7];
    const float* gm = (const float*)d_in[8];
    float* out = (float*)d_out;

    char* ws = (char*)d_ws;
    unsigned short* qTb = (unsigned short*)ws;                      // 512 KB
    unsigned short* kTb = (unsigned short*)(ws + (512 << 10));      // 512 KB
    unsigned short* vB  = (unsigned short*)(ws + (1 << 20));        // 4 MB

    proj<<<576, 256, 0, stream>>>(x, Wq, bq, Wk, bk, xh, Wv, bv, qTb, kTb, vB);
    flash_mfma<<<BB * 128, 256, 0, stream>>>(qTb, kTb, vB, xh, gm, out);
}